// Round 16
// baseline (103.259 us; speedup 1.0000x reference)
//
#include <hip/hip_runtime.h>
#include <hip/hip_bf16.h>

// ---------------- static config ----------------
constexpr int NTOK = 4096;   // 2*2048 tokens
constexpr int DIMD = 1024;   // model dim
constexpr int FINT = 512;    // expert inter dim
constexpr int NEXP = 8;      // routed experts
// TOP_K = 2, ROUTE_SCALE = 1.0

typedef __attribute__((ext_vector_type(8))) short bf16x8;
typedef __attribute__((ext_vector_type(4))) float f32x4;
typedef __attribute__((ext_vector_type(8))) unsigned short u16x8;

__device__ __forceinline__ f32x4 mfma16(bf16x8 a, bf16x8 b, f32x4 c) {
  return __builtin_amdgcn_mfma_f32_16x16x32_bf16(a, b, c, 0, 0, 0);
}

__device__ __forceinline__ void gload16(const void* g, void* l) {
  __builtin_amdgcn_global_load_lds(
      (const __attribute__((address_space(1))) void*)g,
      (__attribute__((address_space(3))) void*)l, 16, 0, 0);
}

__device__ __forceinline__ unsigned short f2bf(float f) {
  unsigned u = __float_as_uint(f);
  u += 0x7fffu + ((u >> 16) & 1u);   // RNE (finite inputs)
  return (unsigned short)(u >> 16);
}

__device__ __forceinline__ float bf2f(unsigned short v) {
  return __uint_as_float((unsigned)v << 16);
}

// ---------------- fused casts; seg0 = gate logits + x->bf16 ----------------
// W1 interleave granularity 16: r = 32*(f>>4) + (up ? 16 : 0) + (f&15).
// Weight segs: 32 elems/thread (8 independent float4 loads) for MLP.
__global__ __launch_bounds__(256) void cast_all(
    const float* __restrict__ x,  const float* __restrict__ wg,
    const float* __restrict__ wu, const float* __restrict__ wd,
    const float* __restrict__ sg, const float* __restrict__ su,
    const float* __restrict__ sd, const float* __restrict__ gw,
    unsigned short* __restrict__ xb,  unsigned short* __restrict__ w1b,
    unsigned short* __restrict__ wdb, unsigned short* __restrict__ s1b,
    unsigned short* __restrict__ sdb,
    int* __restrict__ eid, float2* __restrict__ w12) {
  const int seg = blockIdx.y;

  if (seg == 0) {   // ---- gate: fp64 logits, top-2, softmax; also write xb ----
    if (blockIdx.x >= NTOK / 4) return;
    const int wid = threadIdx.x >> 6;
    const int lane = threadIdx.x & 63;
    const int n = blockIdx.x * 4 + wid;

    const float4* xr = (const float4*)(x + (size_t)n * DIMD);
    float4 xv[4];
#pragma unroll
    for (int j = 0; j < 4; ++j) xv[j] = xr[lane + 64 * j];

    // emit bf16 x row (replaces a separate x-cast segment)
#pragma unroll
    for (int j = 0; j < 4; ++j) {
      ushort4 o;
      o.x = f2bf(xv[j].x); o.y = f2bf(xv[j].y);
      o.z = f2bf(xv[j].z); o.w = f2bf(xv[j].w);
      *(ushort4*)(xb + (size_t)n * DIMD + 4 * (lane + 64 * j)) = o;
    }

    double acc[NEXP];
#pragma unroll
    for (int e = 0; e < NEXP; ++e) {
      const float4* g = (const float4*)(gw + (size_t)e * DIMD);
      double a = 0.0;
#pragma unroll
      for (int j = 0; j < 4; ++j) {
        float4 gv = g[lane + 64 * j];
        a += (double)xv[j].x * (double)gv.x + (double)xv[j].y * (double)gv.y
           + (double)xv[j].z * (double)gv.z + (double)xv[j].w * (double)gv.w;
      }
      acc[e] = a;
    }
#pragma unroll
    for (int e = 0; e < NEXP; ++e) {
#pragma unroll
      for (int off = 32; off > 0; off >>= 1) acc[e] += __shfl_xor(acc[e], off);
    }

    if (lane == 0) {
      float logit[NEXP];
#pragma unroll
      for (int e = 0; e < NEXP; ++e) logit[e] = (float)acc[e];
      int i1 = 0; float v1 = logit[0];
#pragma unroll
      for (int e = 1; e < NEXP; ++e) if (logit[e] > v1) { v1 = logit[e]; i1 = e; }
      int i2 = -1; float v2 = -1e30f;
#pragma unroll
      for (int e = 0; e < NEXP; ++e) if (e != i1 && logit[e] > v2) { v2 = logit[e]; i2 = e; }
      float s = 0.f;
#pragma unroll
      for (int e = 0; e < NEXP; ++e) s += expf(logit[e] - v1);
      eid[n] = i1 | (i2 << 4);
      w12[n] = make_float2(1.f / s, expf(v2 - v1) / s);
    }
    return;
  }

  // ---- weight casts: 32 elements per thread ----
  const int i = blockIdx.x * 256 + threadIdx.x;   // vec32 index
  const float* src; unsigned short* dst;
  size_t si = (size_t)i * 32, di;
  int n32;
  if (seg == 1 || seg == 2) {
    n32 = NEXP * FINT * DIMD / 32; if (i >= n32) return;
    int e = (int)(si >> 19), f = (int)((si >> 10) & 511), d = (int)(si & 1023);
    int r = ((f >> 4) << 5) + (seg == 2 ? 16 : 0) + (f & 15);
    src = (seg == 1) ? wg : wu; dst = w1b;
    di = (((size_t)e << 10) + r) * 1024 + d;
  } else if (seg == 3) {
    n32 = NEXP * DIMD * FINT / 32; if (i >= n32) return;
    src = wd; dst = wdb; di = si;
  } else if (seg == 4 || seg == 5) {
    n32 = FINT * DIMD / 32; if (i >= n32) return;
    int f = (int)((si >> 10) & 511), d = (int)(si & 1023);
    int r = ((f >> 4) << 5) + (seg == 5 ? 16 : 0) + (f & 15);
    src = (seg == 4) ? sg : su; dst = s1b;
    di = (size_t)r * 1024 + d;
  } else {
    n32 = DIMD * FINT / 32; if (i >= n32) return;
    src = sd; dst = sdb; di = si;
  }
  const float4* s4 = (const float4*)(src + si);
  float4 v[8];
#pragma unroll
  for (int j = 0; j < 8; ++j) v[j] = s4[j];   // 8 independent loads in flight
#pragma unroll
  for (int j = 0; j < 4; ++j) {
    u16x8 o;
    o[0] = f2bf(v[2 * j].x); o[1] = f2bf(v[2 * j].y);
    o[2] = f2bf(v[2 * j].z); o[3] = f2bf(v[2 * j].w);
    o[4] = f2bf(v[2 * j + 1].x); o[5] = f2bf(v[2 * j + 1].y);
    o[6] = f2bf(v[2 * j + 1].z); o[7] = f2bf(v[2 * j + 1].w);
    *(u16x8*)(dst + di + j * 8) = o;
  }
}

// ---------------- gate pass 2: deterministic prefix-scan dispatch (1 block) ----
__global__ __launch_bounds__(1024) void dispatch_scan(const int* __restrict__ eid,
                                                      const float2* __restrict__ w12,
                                                      int* __restrict__ cnt,
                                                      int* __restrict__ rowTok,
                                                      float* __restrict__ rowW,
                                                      int2* __restrict__ gslot) {
  const int th = threadIdx.x;          // 0..1023, owns tokens 4th..4th+3
  const int lane = th & 63;
  const int wv = th >> 6;              // 0..15

  int e0[4], e1[4];
  float2 wp[4];
  unsigned long long c0 = 0, c1 = 0;   // packed counts
#pragma unroll
  for (int j = 0; j < 4; ++j) {
    int n = th * 4 + j;
    int p = eid[n];
    wp[j] = w12[n];
    int a = p & 15, b = (p >> 4) & 15;
    e0[j] = a; e1[j] = b;
    unsigned long long ia = 1ull << (16 * (a & 3));
    if (a < 4) c0 += ia; else c1 += ia;
    unsigned long long ib = 1ull << (16 * (b & 3));
    if (b < 4) c0 += ib; else c1 += ib;
  }

  unsigned long long s0 = c0, s1 = c1;
#pragma unroll
  for (int off = 1; off < 64; off <<= 1) {
    unsigned long long u0 = __shfl_up(s0, off);
    unsigned long long u1 = __shfl_up(s1, off);
    if (lane >= off) { s0 += u0; s1 += u1; }
  }

  __shared__ unsigned long long wt0[16], wt1[16];
  __shared__ int ebaseS[NEXP];
  if (lane == 63) { wt0[wv] = s0; wt1[wv] = s1; }
  __syncthreads();

  unsigned long long b0 = 0, b1 = 0;
  for (int w2 = 0; w2 < 16; ++w2)
    if (w2 < wv) { b0 += wt0[w2]; b1 += wt1[w2]; }

  if (th == 0) {
    unsigned long long t0 = 0, t1 = 0;
    for (int w2 = 0; w2 < 16; ++w2) { t0 += wt0[w2]; t1 += wt1[w2]; }
    int tot[NEXP];
#pragma unroll
    for (int e = 0; e < 4; ++e) {
      tot[e]     = (int)((t0 >> (16 * e)) & 0xffff);
      tot[e + 4] = (int)((t1 >> (16 * e)) & 0xffff);
    }
    int run = 0;
#pragma unroll
    for (int e = 0; e < NEXP; ++e) {
      cnt[e] = tot[e];
      cnt[8 + e] = run;
      ebaseS[e] = run;
      run += tot[e];
    }
  }

  unsigned long long x0 = b0 + s0 - c0;
  unsigned long long x1 = b1 + s1 - c1;

  __shared__ unsigned short posL[1024][8];
#pragma unroll
  for (int e = 0; e < 4; ++e) {
    posL[th][e]     = (unsigned short)((x0 >> (16 * e)) & 0xffff);
    posL[th][e + 4] = (unsigned short)((x1 >> (16 * e)) & 0xffff);
  }
  __syncthreads();   // ebaseS visible

#pragma unroll
  for (int j = 0; j < 4; ++j) {
    int n = th * 4 + j;
    int a = e0[j];
    int pa = posL[th][a]; posL[th][a] = (unsigned short)(pa + 1);
    rowTok[a * NTOK + pa] = n; rowW[a * NTOK + pa] = wp[j].x;
    int b = e1[j];
    int pb = posL[th][b]; posL[th][b] = (unsigned short)(pb + 1);
    rowTok[b * NTOK + pb] = n; rowW[b * NTOK + pb] = wp[j].y;
    gslot[n] = make_int2(ebaseS[a] + pa, ebaseS[b] + pb);
  }
}

// ================= 256x256 BK=64 GEMMs, r9/r13 4-phase counted-vmcnt =========
// 512 thr = 8 waves (2M x 4N); per-wave out 128x64; acc 8x4 f32x4.
// LDS 128KB dynamic: A slabs [buf][q] 16KB each, B at +64KB.
// launch_bounds(512,1): 1 block/CU, full VGPR budget (r14 lesson: 2 blocks/CU
// caps waves at 128 VGPR < the ~190 this tile needs -> catastrophic spill).
// Slot swizzle: slot s of row holds chunk s ^ ((row>>1)&3); read
//   koffl = (hi ^ ((fr>>1)&3))*16 -> 0 bank conflicts (measured r7/r9).
// vmcnt ledger: ph0 entry {q0(t),q1(t)}=8 -> vmcnt(4) lands q0;
//               ph2 entry {q1(t),q0(t+1)}=8 -> vmcnt(4) lands q1.

#define GEMM_TILE_LOOP(NT)                                                     \
  STAGE(0, 0, 0);                                                              \
  STAGE(0, 0, 1);                                                              \
  for (int tt = 0; tt < (NT); ++tt) {                                          \
    const int buf = tt & 1;                                                    \
    const unsigned char* LA0 = L + (buf * 2 + 0) * 16384;                      \
    const unsigned char* LB0 = LA0 + 65536;                                    \
    const unsigned char* LA1 = L + (buf * 2 + 1) * 16384;                      \
    const unsigned char* LB1 = LA1 + 65536;                                    \
    bf16x8 Af[4], Bf[4];                                                       \
    /* ---- ph0 ---- */                                                        \
    asm volatile("s_waitcnt vmcnt(4)" ::: "memory");                           \
    __builtin_amdgcn_sched_barrier(0);                                         \
    __builtin_amdgcn_s_barrier();                                              \
    __builtin_amdgcn_sched_barrier(0);                                         \
    _Pragma("unroll")                                                          \
    for (int n = 0; n < 4; ++n)                                                \
      Bf[n] = *(const bf16x8*)(LB0 + (wc * 64 + n * 16 + fr) * 64 + koffl);    \
    _Pragma("unroll")                                                          \
    for (int m = 0; m < 4; ++m)                                                \
      Af[m] = *(const bf16x8*)(LA0 + (wr * 128 + m * 16 + fr) * 64 + koffl);   \
    __builtin_amdgcn_s_setprio(1);                                             \
    _Pragma("unroll")                                                          \
    for (int n = 0; n < 4; ++n)                                                \
      _Pragma("unroll")                                                        \
      for (int m = 0; m < 4; ++m)                                              \
        acc[m][n] = mfma16(Af[m], Bf[n], acc[m][n]);                           \
    __builtin_amdgcn_s_setprio(0);                                             \
    /* ---- ph1 ---- */                                                        \
    if (tt + 1 < (NT)) STAGE(buf ^ 1, tt + 1, 0);                              \
    _Pragma("unroll")                                                          \
    for (int m = 0; m < 4; ++m)                                                \
      Af[m] = *(const bf16x8*)(LA0 + (wr * 128 + (m + 4) * 16 + fr) * 64 + koffl); \
    __builtin_amdgcn_s_setprio(1);                                             \
    _Pragma("unroll")                                                          \
    for (int n = 0; n < 4; ++n)                                                \
      _Pragma("unroll")                                                        \
      for (int m = 0; m < 4; ++m)                                              \
        acc[m + 4][n] = mfma16(Af[m], Bf[n], acc[m + 4][n]);                   \
    __builtin_amdgcn_s_setprio(0);                                             \
    /* ---- ph2 ---- */                                                        \
    if (tt + 1 < (NT)) asm volatile("s_waitcnt vmcnt(4)" ::: "memory");        \
    else               asm volatile("s_waitcnt vmcnt(0)" ::: "memory");        \
    __builtin_amdgcn_sched_barrier(0);                                         \
    __builtin_amdgcn_s_barrier();                                              \
    __builtin_amdgcn_sched_barrier(0);                                         \
    _Pragma("unroll")                                                          \
    for (int n = 0; n < 4; ++n)                                                \
      Bf[n] = *(const bf16x8*)(LB1 + (wc * 64 + n * 16 + fr) * 64 + koffl);    \
    _Pragma("unroll")                                                          \
    for (int m = 0; m < 4; ++m)                                                \
      Af[m] = *(const bf16x8*)(LA1 + (wr * 128 + m * 16 + fr) * 64 + koffl);   \
    __builtin_amdgcn_s_setprio(1);                                             \
    _Pragma("unroll")                                                          \
    for (int n = 0; n < 4; ++n)                                                \
      _Pragma("unroll")                                                        \
      for (int m = 0; m < 4; ++m)                                              \
        acc[m][n] = mfma16(Af[m], Bf[n], acc[m][n]);                           \
    __builtin_amdgcn_s_setprio(0);                                             \
    /* ---- ph3 ---- */                                                        \
    if (tt + 1 < (NT)) STAGE(buf ^ 1, tt + 1, 1);                              \
    _Pragma("unroll")                                                          \
    for (int m = 0; m < 4; ++m)                                                \
      Af[m] = *(const bf16x8*)(LA1 + (wr * 128 + (m + 4) * 16 + fr) * 64 + koffl); \
    __builtin_amdgcn_s_setprio(1);                                             \
    _Pragma("unroll")                                                          \
    for (int n = 0; n < 4; ++n)                                                \
      _Pragma("unroll")                                                        \
      for (int m = 0; m < 4; ++m)                                              \
        acc[m + 4][n] = mfma16(Af[m], Bf[n], acc[m + 4][n]);                   \
    __builtin_amdgcn_s_setprio(0);                                             \
  }

// ---------------- GEMM1: [rows x 1024] @ W1^T -> interleaved g/u, SwiGLU ----
__global__ __launch_bounds__(512, 1) void gemm1_fused(
    const unsigned short* __restrict__ xb,
    const unsigned short* __restrict__ w1b,   // [8][1024][1024]
    const unsigned short* __restrict__ s1b,   // [1024][1024]
    unsigned short* __restrict__ hb,          // [8192][512] compact
    unsigned short* __restrict__ hs,          // [4096][512]
    const int* __restrict__ cnt,
    const int* __restrict__ rowTok,
    const unsigned short* __restrict__ zpg) {
  extern __shared__ unsigned char L[];
  const int e = blockIdx.x >> 2, ty = blockIdx.x & 3;
  const int tx = blockIdx.y;
  const bool RT = (e < NEXP);
  const int Te = RT ? cnt[e] : NTOK;
  const int m0 = tx * 256;
  if (m0 >= Te) return;
  const int n0 = ty * 256;

  const int t = threadIdx.x;
  const int w = t >> 6, lane = t & 63;
  const int wr = w >> 2, wc = w & 3;
  const int fr = lane & 15, hi = lane >> 4;
  const int koffl = ((hi ^ ((fr >> 1) & 3)) << 4);

  const unsigned short* w1e = RT ? w1b + (size_t)e * DIMD * DIMD : s1b;

  const unsigned short* apD[2];
  const unsigned short* bpD[2];
  int aoff[2], boff[2];
#pragma unroll
  for (int j = 0; j < 2; ++j) {
    int c = w * 128 + j * 64 + lane;            // 0..1023
    int rowL = c >> 2;
    int seff = (c & 3) ^ ((c >> 3) & 3);
    int grow = m0 + rowL;
    const unsigned short* p;
    if (RT) p = (grow < Te) ? xb + (size_t)rowTok[e * NTOK + grow] * DIMD : zpg;
    else    p = xb + (size_t)grow * DIMD;
    apD[j] = p + seff * 8;
    bpD[j] = w1e + (size_t)(n0 + rowL) * DIMD + seff * 8;
    aoff[j] = c * 16;
    boff[j] = 65536 + c * 16;
  }

  f32x4 acc[8][4];
  f32x4 zero = {0.f, 0.f, 0.f, 0.f};
#pragma unroll
  for (int m = 0; m < 8; ++m)
#pragma unroll
    for (int n = 0; n < 4; ++n) acc[m][n] = zero;

  auto STAGE = [&](int buf, int tt, int q) {
    int slab = (buf * 2 + q) * 16384;
#pragma unroll
    for (int j = 0; j < 2; ++j) {
      gload16(apD[j] + tt * 64 + q * 32, L + slab + aoff[j]);
      gload16(bpD[j] + tt * 64 + q * 32, L + slab + boff[j]);
    }
  };

  GEMM_TILE_LOOP(DIMD / 64)

  // ---- epilogue: SwiGLU -> LDS (coalesce) -> stream 16B chunks ----
  __syncthreads();
  unsigned short* HL = (unsigned short*)L;     // [256][128] bf16
#pragma unroll
  for (int m = 0; m < 8; ++m) {
#pragma unroll
    for (int r = 0; r < 4; ++r) {
      int rl = wr * 128 + m * 16 + hi * 4 + r;
      float g0 = acc[m][0][r], u0 = acc[m][1][r];
      float g1 = acc[m][2][r], u1 = acc[m][3][r];
      HL[rl * 128 + wc * 32 + fr]      = f2bf(g0 / (1.f + expf(-g0)) * u0);
      HL[rl * 128 + wc * 32 + 16 + fr] = f2bf(g1 / (1.f + expf(-g1)) * u1);
    }
  }
  __syncthreads();
  unsigned short* hbase = RT ? hb + (size_t)cnt[8 + e] * FINT : hs;
  const int f0 = n0 >> 1;
#pragma unroll
  for (int it = 0; it < 8; ++it) {
    int cid = it * 512 + t;            // 4096 chunks = 256 rows x 16
    int row = cid >> 4, c8 = cid & 15;
    if (m0 + row < Te)
      *(u16x8*)(hbase + (size_t)(m0 + row) * FINT + f0 + c8 * 8) =
          *(const u16x8*)(HL + row * 128 + c8 * 8);
  }
}

// ---------------- GEMM2: Y = H @ Wd^T (K=512) -> bf16 ybuf / ys --------------
__global__ __launch_bounds__(512, 1) void gemm2_fused(
    const unsigned short* __restrict__ hb,    // [8192][512] compact
    const unsigned short* __restrict__ hs,    // [4096][512]
    const unsigned short* __restrict__ wdb,   // [8][1024][512]
    const unsigned short* __restrict__ sdb,   // [1024][512]
    unsigned short* __restrict__ ybuf,        // [8192][1024] bf16 (routed, weighted)
    unsigned short* __restrict__ ys,          // [4096][1024] bf16 (shared)
    const int* __restrict__ cnt,
    const float* __restrict__ rowW,
    const unsigned short* __restrict__ zpg) {
  extern __shared__ unsigned char L[];
  const int e = blockIdx.x >> 2, ty = blockIdx.x & 3;
  const int tx = blockIdx.y;
  const bool RT = (e < NEXP);
  const int Te = RT ? cnt[e] : NTOK;
  const int m0 = tx * 256;
  if (m0 >= Te) return;
  const int n0 = ty * 256;

  const int t = threadIdx.x;
  const int w = t >> 6, lane = t & 63;
  const int wr = w >> 2, wc = w & 3;
  const int fr = lane & 15, hi = lane >> 4;
  const int koffl = ((hi ^ ((fr >> 1) & 3)) << 4);

  const int gbase = RT ? cnt[8 + e] : 0;
  const unsigned short* he  = RT ? hb + (size_t)gbase * FINT : hs;
  const unsigned short* wde = RT ? wdb + (size_t)e * DIMD * FINT : sdb;

  const unsigned short* apD[2];
  const unsigned short* bpD[2];
  int aoff[2], boff[2];
#pragma unroll
  for (int j = 0; j < 2; ++j) {
    int c = w * 128 + j * 64 + lane;
    int rowL = c >> 2;
    int seff = (c & 3) ^ ((c >> 3) & 3);
    int grow = m0 + rowL;
    apD[j] = ((grow < Te) ? he + (size_t)grow * FINT : zpg) + seff * 8;
    bpD[j] = wde + (size_t)(n0 + rowL) * FINT + seff * 8;
    aoff[j] = c * 16;
    boff[j] = 65536 + c * 16;
  }

  f32x4 acc[8][4];
  f32x4 zero = {0.f, 0.f, 0.f, 0.f};
#pragma unroll
  for (int m = 0; m < 8; ++m)
#pragma unroll
    for (int n = 0; n < 4; ++n) acc[m][n] = zero;

  auto STAGE = [&](int buf, int tt, int q) {
    int slab = (buf * 2 + q) * 16384;
#pragma unroll
    for (int j = 0; j < 2; ++j) {
      gload16(apD[j] + tt * 64 + q * 32, L + slab + aoff[j]);
      gload16(bpD[j] + tt * 64 + q * 32, L + slab + boff[j]);
    }
  };

  GEMM_TILE_LOOP(FINT / 64)

  // ---- epilogue: weight -> bf16 -> LDS (coalesce) -> stream 16B chunks ----
  __syncthreads();
  unsigned short* YL = (unsigned short*)L;     // [256][256] bf16 = 128KB
#pragma unroll
  for (int m = 0; m < 8; ++m) {
#pragma unroll
    for (int r = 0; r < 4; ++r) {
      int rl = wr * 128 + m * 16 + hi * 4 + r;
      float wt = RT ? rowW[e * NTOK + m0 + rl] : 1.f;
#pragma unroll
      for (int n = 0; n < 4; ++n)
        YL[rl * 256 + wc * 64 + n * 16 + fr] = f2bf(wt * acc[m][n][r]);
    }
  }
  __syncthreads();
  unsigned short* ybase = RT ? ybuf + (size_t)gbase * DIMD : ys;
#pragma unroll
  for (int it = 0; it < 16; ++it) {
    int cid = it * 512 + t;            // 8192 chunks = 256 rows x 32
    int row = cid >> 5, c8 = cid & 31;
    if (m0 + row < Te)
      *(u16x8*)(ybase + (size_t)(m0 + row) * DIMD + n0 + c8 * 8) =
          *(const u16x8*)(YL + row * 256 + c8 * 8);
  }
}

// ---------------- combine: out[n] = ys[n] + ybuf[gs1] + ybuf[gs2] ------------
__global__ __launch_bounds__(256) void combine(const unsigned short* __restrict__ ybuf,
                                               const unsigned short* __restrict__ ys,
                                               const int2* __restrict__ gslot,
                                               float* __restrict__ out) {
  const int n = blockIdx.x;
  const int t = threadIdx.x;            // 256 threads x 4 elems
  int2 gs = gslot[n];
  ushort4 a = ((const ushort4*)(ybuf + (size_t)gs.x * DIMD))[t];
  ushort4 b = ((const ushort4*)(ybuf + (size_t)gs.y * DIMD))[t];
  ushort4 c = ((const ushort4*)(ys + (size_t)n * DIMD))[t];
  float4 o;
  o.x = bf2f(c.x) + bf2f(a.x) + bf2f(b.x);
  o.y = bf2f(c.y) + bf2f(a.y) + bf2f(b.y);
  o.z = bf2f(c.z) + bf2f(a.z) + bf2f(b.z);
  o.w = bf2f(c.w) + bf2f(a.w) + bf2f(b.w);
  ((float4*)(out + (size_t)n * DIMD))[t] = o;
}

// ---------------- launch ----------------
extern "C" void kernel_launch(void* const* d_in, const int* in_sizes, int n_in,
                              void* d_out, int out_size, void* d_ws, size_t ws_size,
                              hipStream_t stream) {
  const float* x  = (const float*)d_in[0];
  const float* gw = (const float*)d_in[1];
  const float* wg = (const float*)d_in[2];
  const float* wu = (const float*)d_in[3];
  const float* wd = (const float*)d_in[4];
  const float* sg = (const float*)d_in[5];
  const float* su = (const float*)d_in[6];
  const float* sd = (const float*)d_in[7];
  float* out = (float*)d_out;

  char* ws = (char*)d_ws;
  size_t off = 0;
  auto alloc = [&](size_t bytes) -> char* {
    char* p = ws + off;
    off += (bytes + 255) & ~(size_t)255;
    return p;
  };
  unsigned short* xb  = (unsigned short*)alloc((size_t)NTOK * DIMD * 2);
  unsigned short* w1b = (unsigned short*)alloc((size_t)NEXP * DIMD * DIMD * 2);
  unsigned short* wdb = (unsigned short*)alloc((size_t)NEXP * DIMD * FINT * 2);
  unsigned short* s1b = (unsigned short*)alloc((size_t)DIMD * DIMD * 2);
  unsigned short* sdb = (unsigned short*)alloc((size_t)DIMD * FINT * 2);
  unsigned short* hb  = (unsigned short*)alloc((size_t)2 * NTOK * FINT * 2);  // 8192 rows compact
  unsigned short* hs  = (unsigned short*)alloc((size_t)NTOK * FINT * 2);
  unsigned short* ybuf= (unsigned short*)alloc((size_t)2 * NTOK * DIMD * 2);  // bf16
  unsigned short* ys  = (unsigned short*)alloc((size_t)NTOK * DIMD * 2);      // bf16
  int*            cnt = (int*)alloc(256);
  int*         rowTok = (int*)alloc((size_t)NEXP * NTOK * 4);
  float*         rowW = (float*)alloc((size_t)NEXP * NTOK * 4);
  unsigned short* zpg = (unsigned short*)alloc((size_t)DIMD * 2);
  int*            eid = (int*)alloc((size_t)NTOK * 4);
  float2*         w12 = (float2*)alloc((size_t)NTOK * 8);
  int2*         gslot = (int2*)alloc((size_t)NTOK * 8);
  if (off > ws_size) return;  // ws too small: fail loudly (out stays poisoned)

  hipFuncSetAttribute((const void*)gemm1_fused,
                      hipFuncAttributeMaxDynamicSharedMemorySize, 131072);
  hipFuncSetAttribute((const void*)gemm2_fused,
                      hipFuncAttributeMaxDynamicSharedMemorySize, 131072);

  hipMemsetAsync(zpg, 0, (size_t)DIMD * 2, stream);

  cast_all<<<dim3(1024, 7), 256, 0, stream>>>(x, wg, wu, wd, sg, su, sd, gw,
                                              xb, w1b, wdb, s1b, sdb, eid, w12);

  dispatch_scan<<<1, 1024, 0, stream>>>(eid, w12, cnt, rowTok, rowW, gslot);

  gemm1_fused<<<dim3(36, 16), 512, 131072, stream>>>(xb, w1b, s1b, hb, hs,
                                                     cnt, rowTok, zpg);
  gemm2_fused<<<dim3(36, 16), 512, 131072, stream>>>(hb, hs, wdb, sdb, ybuf, ys,
                                                     cnt, rowW, zpg);
  combine<<<NTOK, 256, 0, stream>>>(ybuf, ys, gslot, out);
}

// Round 17
// 100.586 us; speedup vs baseline: 1.0266x; 1.0266x over previous
//
#include <hip/hip_runtime.h>
#include <hip/hip_bf16.h>

// ---------------- static config ----------------
constexpr int NTOK = 4096;   // 2*2048 tokens
constexpr int DIMD = 1024;   // model dim
constexpr int FINT = 512;    // expert inter dim
constexpr int NEXP = 8;      // routed experts
// TOP_K = 2, ROUTE_SCALE = 1.0

typedef __attribute__((ext_vector_type(8))) short bf16x8;
typedef __attribute__((ext_vector_type(4))) float f32x4;
typedef __attribute__((ext_vector_type(8))) unsigned short u16x8;

__device__ __forceinline__ f32x4 mfma16(bf16x8 a, bf16x8 b, f32x4 c) {
  return __builtin_amdgcn_mfma_f32_16x16x32_bf16(a, b, c, 0, 0, 0);
}

__device__ __forceinline__ void gload16(const void* g, void* l) {
  __builtin_amdgcn_global_load_lds(
      (const __attribute__((address_space(1))) void*)g,
      (__attribute__((address_space(3))) void*)l, 16, 0, 0);
}

__device__ __forceinline__ unsigned short f2bf(float f) {
  unsigned u = __float_as_uint(f);
  u += 0x7fffu + ((u >> 16) & 1u);   // RNE (finite inputs)
  return (unsigned short)(u >> 16);
}

__device__ __forceinline__ float bf2f(unsigned short v) {
  return __uint_as_float((unsigned)v << 16);
}

// ---------------- fused casts; seg0 = gate logits + x->bf16 ----------------
// W1 interleave granularity 16: r = 32*(f>>4) + (up ? 16 : 0) + (f&15).
__global__ __launch_bounds__(256) void cast_all(
    const float* __restrict__ x,  const float* __restrict__ wg,
    const float* __restrict__ wu, const float* __restrict__ wd,
    const float* __restrict__ sg, const float* __restrict__ su,
    const float* __restrict__ sd, const float* __restrict__ gw,
    unsigned short* __restrict__ xb,  unsigned short* __restrict__ w1b,
    unsigned short* __restrict__ wdb, unsigned short* __restrict__ s1b,
    unsigned short* __restrict__ sdb,
    int* __restrict__ eid, float2* __restrict__ w12) {
  const int seg = blockIdx.y;

  if (seg == 0) {   // ---- gate: fp64 logits, top-2, softmax; also write xb ----
    if (blockIdx.x >= NTOK / 4) return;
    const int wid = threadIdx.x >> 6;
    const int lane = threadIdx.x & 63;
    const int n = blockIdx.x * 4 + wid;

    const float4* xr = (const float4*)(x + (size_t)n * DIMD);
    float4 xv[4];
#pragma unroll
    for (int j = 0; j < 4; ++j) xv[j] = xr[lane + 64 * j];

    // emit bf16 x row (replaces a separate x-cast segment)
#pragma unroll
    for (int j = 0; j < 4; ++j) {
      ushort4 o;
      o.x = f2bf(xv[j].x); o.y = f2bf(xv[j].y);
      o.z = f2bf(xv[j].z); o.w = f2bf(xv[j].w);
      *(ushort4*)(xb + (size_t)n * DIMD + 4 * (lane + 64 * j)) = o;
    }

    double acc[NEXP];
#pragma unroll
    for (int e = 0; e < NEXP; ++e) {
      const float4* g = (const float4*)(gw + (size_t)e * DIMD);
      double a = 0.0;
#pragma unroll
      for (int j = 0; j < 4; ++j) {
        float4 gv = g[lane + 64 * j];
        a += (double)xv[j].x * (double)gv.x + (double)xv[j].y * (double)gv.y
           + (double)xv[j].z * (double)gv.z + (double)xv[j].w * (double)gv.w;
      }
      acc[e] = a;
    }
#pragma unroll
    for (int e = 0; e < NEXP; ++e) {
#pragma unroll
      for (int off = 32; off > 0; off >>= 1) acc[e] += __shfl_xor(acc[e], off);
    }

    if (lane == 0) {
      float logit[NEXP];
#pragma unroll
      for (int e = 0; e < NEXP; ++e) logit[e] = (float)acc[e];
      int i1 = 0; float v1 = logit[0];
#pragma unroll
      for (int e = 1; e < NEXP; ++e) if (logit[e] > v1) { v1 = logit[e]; i1 = e; }
      int i2 = -1; float v2 = -1e30f;
#pragma unroll
      for (int e = 0; e < NEXP; ++e) if (e != i1 && logit[e] > v2) { v2 = logit[e]; i2 = e; }
      float s = 0.f;
#pragma unroll
      for (int e = 0; e < NEXP; ++e) s += expf(logit[e] - v1);
      eid[n] = i1 | (i2 << 4);
      w12[n] = make_float2(1.f / s, expf(v2 - v1) / s);
    }
    return;
  }

  const int i = blockIdx.x * 256 + threadIdx.x;   // vec8 index
  const float* src; unsigned short* dst;
  size_t si = (size_t)i * 8, di;
  int n8;
  if (seg == 1 || seg == 2) {
    n8 = NEXP * FINT * DIMD / 8; if (i >= n8) return;
    int e = (int)(si >> 19), f = (int)((si >> 10) & 511), d = (int)(si & 1023);
    int r = ((f >> 4) << 5) + (seg == 2 ? 16 : 0) + (f & 15);
    src = (seg == 1) ? wg : wu; dst = w1b;
    di = (((size_t)e << 10) + r) * 1024 + d;
  } else if (seg == 3) {
    n8 = NEXP * DIMD * FINT / 8; if (i >= n8) return;
    src = wd; dst = wdb; di = si;
  } else if (seg == 4 || seg == 5) {
    n8 = FINT * DIMD / 8; if (i >= n8) return;
    int f = (int)((si >> 10) & 511), d = (int)(si & 1023);
    int r = ((f >> 4) << 5) + (seg == 5 ? 16 : 0) + (f & 15);
    src = (seg == 4) ? sg : su; dst = s1b;
    di = (size_t)r * 1024 + d;
  } else {
    n8 = DIMD * FINT / 8; if (i >= n8) return;
    src = sd; dst = sdb; di = si;
  }
  const float4* s4 = (const float4*)(src + si);
  float4 a = s4[0], b = s4[1];
  u16x8 o;
  o[0] = f2bf(a.x); o[1] = f2bf(a.y); o[2] = f2bf(a.z); o[3] = f2bf(a.w);
  o[4] = f2bf(b.x); o[5] = f2bf(b.y); o[6] = f2bf(b.z); o[7] = f2bf(b.w);
  *(u16x8*)(dst + di) = o;
}

// ---------------- gate pass 2: deterministic prefix-scan dispatch (1 block) ----
__global__ __launch_bounds__(1024) void dispatch_scan(const int* __restrict__ eid,
                                                      const float2* __restrict__ w12,
                                                      int* __restrict__ cnt,
                                                      int* __restrict__ rowTok,
                                                      float* __restrict__ rowW,
                                                      int2* __restrict__ gslot) {
  const int th = threadIdx.x;          // 0..1023, owns tokens 4th..4th+3
  const int lane = th & 63;
  const int wv = th >> 6;              // 0..15

  int e0[4], e1[4];
  float2 wp[4];
  unsigned long long c0 = 0, c1 = 0;   // packed counts
#pragma unroll
  for (int j = 0; j < 4; ++j) {
    int n = th * 4 + j;
    int p = eid[n];
    wp[j] = w12[n];
    int a = p & 15, b = (p >> 4) & 15;
    e0[j] = a; e1[j] = b;
    unsigned long long ia = 1ull << (16 * (a & 3));
    if (a < 4) c0 += ia; else c1 += ia;
    unsigned long long ib = 1ull << (16 * (b & 3));
    if (b < 4) c0 += ib; else c1 += ib;
  }

  unsigned long long s0 = c0, s1 = c1;
#pragma unroll
  for (int off = 1; off < 64; off <<= 1) {
    unsigned long long u0 = __shfl_up(s0, off);
    unsigned long long u1 = __shfl_up(s1, off);
    if (lane >= off) { s0 += u0; s1 += u1; }
  }

  __shared__ unsigned long long wt0[16], wt1[16];
  __shared__ int ebaseS[NEXP];
  if (lane == 63) { wt0[wv] = s0; wt1[wv] = s1; }
  __syncthreads();

  unsigned long long b0 = 0, b1 = 0;
  for (int w2 = 0; w2 < 16; ++w2)
    if (w2 < wv) { b0 += wt0[w2]; b1 += wt1[w2]; }

  if (th == 0) {
    unsigned long long t0 = 0, t1 = 0;
    for (int w2 = 0; w2 < 16; ++w2) { t0 += wt0[w2]; t1 += wt1[w2]; }
    int tot[NEXP];
#pragma unroll
    for (int e = 0; e < 4; ++e) {
      tot[e]     = (int)((t0 >> (16 * e)) & 0xffff);
      tot[e + 4] = (int)((t1 >> (16 * e)) & 0xffff);
    }
    int run = 0;
#pragma unroll
    for (int e = 0; e < NEXP; ++e) {
      cnt[e] = tot[e];
      cnt[8 + e] = run;
      ebaseS[e] = run;
      run += tot[e];
    }
  }

  unsigned long long x0 = b0 + s0 - c0;
  unsigned long long x1 = b1 + s1 - c1;

  __shared__ unsigned short posL[1024][8];
#pragma unroll
  for (int e = 0; e < 4; ++e) {
    posL[th][e]     = (unsigned short)((x0 >> (16 * e)) & 0xffff);
    posL[th][e + 4] = (unsigned short)((x1 >> (16 * e)) & 0xffff);
  }
  __syncthreads();   // ebaseS visible

#pragma unroll
  for (int j = 0; j < 4; ++j) {
    int n = th * 4 + j;
    int a = e0[j];
    int pa = posL[th][a]; posL[th][a] = (unsigned short)(pa + 1);
    rowTok[a * NTOK + pa] = n; rowW[a * NTOK + pa] = wp[j].x;
    int b = e1[j];
    int pb = posL[th][b]; posL[th][b] = (unsigned short)(pb + 1);
    rowTok[b * NTOK + pb] = n; rowW[b * NTOK + pb] = wp[j].y;
    gslot[n] = make_int2(ebaseS[a] + pa, ebaseS[b] + pb);
  }
}

// ================= 256x256 BK=64 GEMMs, r9/r13 4-phase counted-vmcnt =========
// 512 thr = 8 waves (2M x 4N); per-wave out 128x64; acc 8x4 f32x4.
// LDS 128KB dynamic: A slabs [buf][q] 16KB each, B at +64KB.
// launch_bounds(512,1): 1 block/CU, full VGPR budget (r14 lesson: 2 blocks/CU
// caps waves at 128 VGPR < the ~190 this tile needs -> catastrophic spill).
// Slot swizzle: slot s of row holds chunk s ^ ((row>>1)&3); read
//   koffl = (hi ^ ((fr>>1)&3))*16 -> 0 bank conflicts (measured r7/r9).
// vmcnt ledger: ph0 entry {q0(t),q1(t)}=8 -> vmcnt(4) lands q0;
//               ph2 entry {q1(t),q0(t+1)}=8 -> vmcnt(4) lands q1.

#define GEMM_TILE_LOOP(NT)                                                     \
  STAGE(0, 0, 0);                                                              \
  STAGE(0, 0, 1);                                                              \
  for (int tt = 0; tt < (NT); ++tt) {                                          \
    const int buf = tt & 1;                                                    \
    const unsigned char* LA0 = L + (buf * 2 + 0) * 16384;                      \
    const unsigned char* LB0 = LA0 + 65536;                                    \
    const unsigned char* LA1 = L + (buf * 2 + 1) * 16384;                      \
    const unsigned char* LB1 = LA1 + 65536;                                    \
    bf16x8 Af[4], Bf[4];                                                       \
    /* ---- ph0 ---- */                                                        \
    asm volatile("s_waitcnt vmcnt(4)" ::: "memory");                           \
    __builtin_amdgcn_sched_barrier(0);                                         \
    __builtin_amdgcn_s_barrier();                                              \
    __builtin_amdgcn_sched_barrier(0);                                         \
    _Pragma("unroll")                                                          \
    for (int n = 0; n < 4; ++n)                                                \
      Bf[n] = *(const bf16x8*)(LB0 + (wc * 64 + n * 16 + fr) * 64 + koffl);    \
    _Pragma("unroll")                                                          \
    for (int m = 0; m < 4; ++m)                                                \
      Af[m] = *(const bf16x8*)(LA0 + (wr * 128 + m * 16 + fr) * 64 + koffl);   \
    __builtin_amdgcn_s_setprio(1);                                             \
    _Pragma("unroll")                                                          \
    for (int n = 0; n < 4; ++n)                                                \
      _Pragma("unroll")                                                        \
      for (int m = 0; m < 4; ++m)                                              \
        acc[m][n] = mfma16(Af[m], Bf[n], acc[m][n]);                           \
    __builtin_amdgcn_s_setprio(0);                                             \
    /* ---- ph1 ---- */                                                        \
    if (tt + 1 < (NT)) STAGE(buf ^ 1, tt + 1, 0);                              \
    _Pragma("unroll")                                                          \
    for (int m = 0; m < 4; ++m)                                                \
      Af[m] = *(const bf16x8*)(LA0 + (wr * 128 + (m + 4) * 16 + fr) * 64 + koffl); \
    __builtin_amdgcn_s_setprio(1);                                             \
    _Pragma("unroll")                                                          \
    for (int n = 0; n < 4; ++n)                                                \
      _Pragma("unroll")                                                        \
      for (int m = 0; m < 4; ++m)                                              \
        acc[m + 4][n] = mfma16(Af[m], Bf[n], acc[m + 4][n]);                   \
    __builtin_amdgcn_s_setprio(0);                                             \
    /* ---- ph2 ---- */                                                        \
    if (tt + 1 < (NT)) asm volatile("s_waitcnt vmcnt(4)" ::: "memory");        \
    else               asm volatile("s_waitcnt vmcnt(0)" ::: "memory");        \
    __builtin_amdgcn_sched_barrier(0);                                         \
    __builtin_amdgcn_s_barrier();                                              \
    __builtin_amdgcn_sched_barrier(0);                                         \
    _Pragma("unroll")                                                          \
    for (int n = 0; n < 4; ++n)                                                \
      Bf[n] = *(const bf16x8*)(LB1 + (wc * 64 + n * 16 + fr) * 64 + koffl);    \
    _Pragma("unroll")                                                          \
    for (int m = 0; m < 4; ++m)                                                \
      Af[m] = *(const bf16x8*)(LA1 + (wr * 128 + m * 16 + fr) * 64 + koffl);   \
    __builtin_amdgcn_s_setprio(1);                                             \
    _Pragma("unroll")                                                          \
    for (int n = 0; n < 4; ++n)                                                \
      _Pragma("unroll")                                                        \
      for (int m = 0; m < 4; ++m)                                              \
        acc[m][n] = mfma16(Af[m], Bf[n], acc[m][n]);                           \
    __builtin_amdgcn_s_setprio(0);                                             \
    /* ---- ph3 ---- */                                                        \
    if (tt + 1 < (NT)) STAGE(buf ^ 1, tt + 1, 1);                              \
    _Pragma("unroll")                                                          \
    for (int m = 0; m < 4; ++m)                                                \
      Af[m] = *(const bf16x8*)(LA1 + (wr * 128 + (m + 4) * 16 + fr) * 64 + koffl); \
    __builtin_amdgcn_s_setprio(1);                                             \
    _Pragma("unroll")                                                          \
    for (int n = 0; n < 4; ++n)                                                \
      _Pragma("unroll")                                                        \
      for (int m = 0; m < 4; ++m)                                              \
        acc[m + 4][n] = mfma16(Af[m], Bf[n], acc[m + 4][n]);                   \
    __builtin_amdgcn_s_setprio(0);                                             \
  }

// ---------------- GEMM1: [rows x 1024] @ W1^T -> interleaved g/u, SwiGLU ----
__global__ __launch_bounds__(512, 1) void gemm1_fused(
    const unsigned short* __restrict__ xb,
    const unsigned short* __restrict__ w1b,   // [8][1024][1024]
    const unsigned short* __restrict__ s1b,   // [1024][1024]
    unsigned short* __restrict__ hb,          // [8192][512] compact
    unsigned short* __restrict__ hs,          // [4096][512]
    const int* __restrict__ cnt,
    const int* __restrict__ rowTok,
    const unsigned short* __restrict__ zpg) {
  extern __shared__ unsigned char L[];
  const int e = blockIdx.x >> 2, ty = blockIdx.x & 3;
  const int tx = blockIdx.y;
  const bool RT = (e < NEXP);
  const int Te = RT ? cnt[e] : NTOK;
  const int m0 = tx * 256;
  if (m0 >= Te) return;
  const int n0 = ty * 256;

  const int t = threadIdx.x;
  const int w = t >> 6, lane = t & 63;
  const int wr = w >> 2, wc = w & 3;
  const int fr = lane & 15, hi = lane >> 4;
  const int koffl = ((hi ^ ((fr >> 1) & 3)) << 4);

  const unsigned short* w1e = RT ? w1b + (size_t)e * DIMD * DIMD : s1b;

  const unsigned short* apD[2];
  const unsigned short* bpD[2];
  int aoff[2], boff[2];
#pragma unroll
  for (int j = 0; j < 2; ++j) {
    int c = w * 128 + j * 64 + lane;            // 0..1023
    int rowL = c >> 2;
    int seff = (c & 3) ^ ((c >> 3) & 3);
    int grow = m0 + rowL;
    const unsigned short* p;
    if (RT) p = (grow < Te) ? xb + (size_t)rowTok[e * NTOK + grow] * DIMD : zpg;
    else    p = xb + (size_t)grow * DIMD;
    apD[j] = p + seff * 8;
    bpD[j] = w1e + (size_t)(n0 + rowL) * DIMD + seff * 8;
    aoff[j] = c * 16;
    boff[j] = 65536 + c * 16;
  }

  f32x4 acc[8][4];
  f32x4 zero = {0.f, 0.f, 0.f, 0.f};
#pragma unroll
  for (int m = 0; m < 8; ++m)
#pragma unroll
    for (int n = 0; n < 4; ++n) acc[m][n] = zero;

  auto STAGE = [&](int buf, int tt, int q) {
    int slab = (buf * 2 + q) * 16384;
#pragma unroll
    for (int j = 0; j < 2; ++j) {
      gload16(apD[j] + tt * 64 + q * 32, L + slab + aoff[j]);
      gload16(bpD[j] + tt * 64 + q * 32, L + slab + boff[j]);
    }
  };

  GEMM_TILE_LOOP(DIMD / 64)

  // ---- epilogue: SwiGLU -> LDS (coalesce) -> stream 16B chunks ----
  __syncthreads();
  unsigned short* HL = (unsigned short*)L;     // [256][128] bf16
#pragma unroll
  for (int m = 0; m < 8; ++m) {
#pragma unroll
    for (int r = 0; r < 4; ++r) {
      int rl = wr * 128 + m * 16 + hi * 4 + r;
      float g0 = acc[m][0][r], u0 = acc[m][1][r];
      float g1 = acc[m][2][r], u1 = acc[m][3][r];
      HL[rl * 128 + wc * 32 + fr]      = f2bf(g0 / (1.f + expf(-g0)) * u0);
      HL[rl * 128 + wc * 32 + 16 + fr] = f2bf(g1 / (1.f + expf(-g1)) * u1);
    }
  }
  __syncthreads();
  unsigned short* hbase = RT ? hb + (size_t)cnt[8 + e] * FINT : hs;
  const int f0 = n0 >> 1;
#pragma unroll
  for (int it = 0; it < 8; ++it) {
    int cid = it * 512 + t;            // 4096 chunks = 256 rows x 16
    int row = cid >> 4, c8 = cid & 15;
    if (m0 + row < Te)
      *(u16x8*)(hbase + (size_t)(m0 + row) * FINT + f0 + c8 * 8) =
          *(const u16x8*)(HL + row * 128 + c8 * 8);
  }
}

// ---------------- GEMM2: Y = H @ Wd^T (K=512) -> bf16 ybuf / ys --------------
__global__ __launch_bounds__(512, 1) void gemm2_fused(
    const unsigned short* __restrict__ hb,    // [8192][512] compact
    const unsigned short* __restrict__ hs,    // [4096][512]
    const unsigned short* __restrict__ wdb,   // [8][1024][512]
    const unsigned short* __restrict__ sdb,   // [1024][512]
    unsigned short* __restrict__ ybuf,        // [8192][1024] bf16 (routed, weighted)
    unsigned short* __restrict__ ys,          // [4096][1024] bf16 (shared)
    const int* __restrict__ cnt,
    const float* __restrict__ rowW,
    const unsigned short* __restrict__ zpg) {
  extern __shared__ unsigned char L[];
  const int e = blockIdx.x >> 2, ty = blockIdx.x & 3;
  const int tx = blockIdx.y;
  const bool RT = (e < NEXP);
  const int Te = RT ? cnt[e] : NTOK;
  const int m0 = tx * 256;
  if (m0 >= Te) return;
  const int n0 = ty * 256;

  const int t = threadIdx.x;
  const int w = t >> 6, lane = t & 63;
  const int wr = w >> 2, wc = w & 3;
  const int fr = lane & 15, hi = lane >> 4;
  const int koffl = ((hi ^ ((fr >> 1) & 3)) << 4);

  const int gbase = RT ? cnt[8 + e] : 0;
  const unsigned short* he  = RT ? hb + (size_t)gbase * FINT : hs;
  const unsigned short* wde = RT ? wdb + (size_t)e * DIMD * FINT : sdb;

  const unsigned short* apD[2];
  const unsigned short* bpD[2];
  int aoff[2], boff[2];
#pragma unroll
  for (int j = 0; j < 2; ++j) {
    int c = w * 128 + j * 64 + lane;
    int rowL = c >> 2;
    int seff = (c & 3) ^ ((c >> 3) & 3);
    int grow = m0 + rowL;
    apD[j] = ((grow < Te) ? he + (size_t)grow * FINT : zpg) + seff * 8;
    bpD[j] = wde + (size_t)(n0 + rowL) * FINT + seff * 8;
    aoff[j] = c * 16;
    boff[j] = 65536 + c * 16;
  }

  f32x4 acc[8][4];
  f32x4 zero = {0.f, 0.f, 0.f, 0.f};
#pragma unroll
  for (int m = 0; m < 8; ++m)
#pragma unroll
    for (int n = 0; n < 4; ++n) acc[m][n] = zero;

  auto STAGE = [&](int buf, int tt, int q) {
    int slab = (buf * 2 + q) * 16384;
#pragma unroll
    for (int j = 0; j < 2; ++j) {
      gload16(apD[j] + tt * 64 + q * 32, L + slab + aoff[j]);
      gload16(bpD[j] + tt * 64 + q * 32, L + slab + boff[j]);
    }
  };

  GEMM_TILE_LOOP(FINT / 64)

  // ---- epilogue: weight -> bf16 -> LDS (coalesce) -> stream 16B chunks ----
  __syncthreads();
  unsigned short* YL = (unsigned short*)L;     // [256][256] bf16 = 128KB
#pragma unroll
  for (int m = 0; m < 8; ++m) {
#pragma unroll
    for (int r = 0; r < 4; ++r) {
      int rl = wr * 128 + m * 16 + hi * 4 + r;
      float wt = RT ? rowW[e * NTOK + m0 + rl] : 1.f;
#pragma unroll
      for (int n = 0; n < 4; ++n)
        YL[rl * 256 + wc * 64 + n * 16 + fr] = f2bf(wt * acc[m][n][r]);
    }
  }
  __syncthreads();
  unsigned short* ybase = RT ? ybuf + (size_t)gbase * DIMD : ys;
#pragma unroll
  for (int it = 0; it < 16; ++it) {
    int cid = it * 512 + t;            // 8192 chunks = 256 rows x 32
    int row = cid >> 5, c8 = cid & 31;
    if (m0 + row < Te)
      *(u16x8*)(ybase + (size_t)(m0 + row) * DIMD + n0 + c8 * 8) =
          *(const u16x8*)(YL + row * 256 + c8 * 8);
  }
}

// ---------------- combine: out[n] = ys[n] + ybuf[gs1] + ybuf[gs2] ------------
__global__ __launch_bounds__(256) void combine(const unsigned short* __restrict__ ybuf,
                                               const unsigned short* __restrict__ ys,
                                               const int2* __restrict__ gslot,
                                               float* __restrict__ out) {
  const int n = blockIdx.x;
  const int t = threadIdx.x;            // 256 threads x 4 elems
  int2 gs = gslot[n];
  ushort4 a = ((const ushort4*)(ybuf + (size_t)gs.x * DIMD))[t];
  ushort4 b = ((const ushort4*)(ybuf + (size_t)gs.y * DIMD))[t];
  ushort4 c = ((const ushort4*)(ys + (size_t)n * DIMD))[t];
  float4 o;
  o.x = bf2f(c.x) + bf2f(a.x) + bf2f(b.x);
  o.y = bf2f(c.y) + bf2f(a.y) + bf2f(b.y);
  o.z = bf2f(c.z) + bf2f(a.z) + bf2f(b.z);
  o.w = bf2f(c.w) + bf2f(a.w) + bf2f(b.w);
  ((float4*)(out + (size_t)n * DIMD))[t] = o;
}

// ---------------- launch ----------------
extern "C" void kernel_launch(void* const* d_in, const int* in_sizes, int n_in,
                              void* d_out, int out_size, void* d_ws, size_t ws_size,
                              hipStream_t stream) {
  const float* x  = (const float*)d_in[0];
  const float* gw = (const float*)d_in[1];
  const float* wg = (const float*)d_in[2];
  const float* wu = (const float*)d_in[3];
  const float* wd = (const float*)d_in[4];
  const float* sg = (const float*)d_in[5];
  const float* su = (const float*)d_in[6];
  const float* sd = (const float*)d_in[7];
  float* out = (float*)d_out;

  char* ws = (char*)d_ws;
  size_t off = 0;
  auto alloc = [&](size_t bytes) -> char* {
    char* p = ws + off;
    off += (bytes + 255) & ~(size_t)255;
    return p;
  };
  unsigned short* xb  = (unsigned short*)alloc((size_t)NTOK * DIMD * 2);
  unsigned short* w1b = (unsigned short*)alloc((size_t)NEXP * DIMD * DIMD * 2);
  unsigned short* wdb = (unsigned short*)alloc((size_t)NEXP * DIMD * FINT * 2);
  unsigned short* s1b = (unsigned short*)alloc((size_t)DIMD * DIMD * 2);
  unsigned short* sdb = (unsigned short*)alloc((size_t)DIMD * FINT * 2);
  unsigned short* hb  = (unsigned short*)alloc((size_t)2 * NTOK * FINT * 2);  // 8192 rows compact
  unsigned short* hs  = (unsigned short*)alloc((size_t)NTOK * FINT * 2);
  unsigned short* ybuf= (unsigned short*)alloc((size_t)2 * NTOK * DIMD * 2);  // bf16
  unsigned short* ys  = (unsigned short*)alloc((size_t)NTOK * DIMD * 2);      // bf16
  int*            cnt = (int*)alloc(256);
  int*         rowTok = (int*)alloc((size_t)NEXP * NTOK * 4);
  float*         rowW = (float*)alloc((size_t)NEXP * NTOK * 4);
  unsigned short* zpg = (unsigned short*)alloc((size_t)DIMD * 2);
  int*            eid = (int*)alloc((size_t)NTOK * 4);
  float2*         w12 = (float2*)alloc((size_t)NTOK * 8);
  int2*         gslot = (int2*)alloc((size_t)NTOK * 8);
  if (off > ws_size) return;  // ws too small: fail loudly (out stays poisoned)

  hipFuncSetAttribute((const void*)gemm1_fused,
                      hipFuncAttributeMaxDynamicSharedMemorySize, 131072);
  hipFuncSetAttribute((const void*)gemm2_fused,
                      hipFuncAttributeMaxDynamicSharedMemorySize, 131072);

  hipMemsetAsync(zpg, 0, (size_t)DIMD * 2, stream);

  cast_all<<<dim3(2048, 7), 256, 0, stream>>>(x, wg, wu, wd, sg, su, sd, gw,
                                              xb, w1b, wdb, s1b, sdb, eid, w12);

  dispatch_scan<<<1, 1024, 0, stream>>>(eid, w12, cnt, rowTok, rowW, gslot);

  gemm1_fused<<<dim3(36, 16), 512, 131072, stream>>>(xb, w1b, s1b, hb, hs,
                                                     cnt, rowTok, zpg);
  gemm2_fused<<<dim3(36, 16), 512, 131072, stream>>>(hb, hs, wdb, sdb, ybuf, ys,
                                                     cnt, rowW, zpg);
  combine<<<NTOK, 256, 0, stream>>>(ybuf, ys, gslot, out);
}